// Round 3
// baseline (210.598 us; speedup 1.0000x reference)
//
#include <hip/hip_runtime.h>

#define NL 64
#define NT 512
#define BB 8
#define HH 128
#define NE 2048
#define NM 4096

static constexpr size_t OUT_PI = 0;
static constexpr size_t OUT_SG = 2621440;
static constexpr size_t OUT_MU = 5242880;
static constexpr size_t OUT_CB = 7864320;
static constexpr size_t OUT_AT = 8126464;
static constexpr size_t OUT_BT = 8135680;
static constexpr size_t OUT_CD = 8145920;
static constexpr size_t OUT_CM = 8150016;

__device__ __forceinline__ float bf2f(ushort u) {
    union { uint i; float f; } v; v.i = ((uint)u) << 16; return v.f;
}
__device__ __forceinline__ float bflo(uint u) {
    union { uint i; float f; } v; v.i = u << 16; return v.f;
}
__device__ __forceinline__ float bfhi(uint u) {
    union { uint i; float f; } v; v.i = u & 0xffff0000u; return v.f;
}
__device__ __forceinline__ ushort f2bf(float f) {
    union { float f; uint u; } v; v.f = f;
    uint u = v.u + 0x7fffu + ((v.u >> 16) & 1u);
    return (ushort)(u >> 16);
}
__device__ __forceinline__ float eluf(float x) { return x > 0.f ? x : (__expf(x) - 1.f); }

// dtype-dual load: float buffers load direct, bf16 buffers decode
__device__ __forceinline__ float ldv(const float* p, int i) { return p[i]; }
__device__ __forceinline__ float ldv(const ushort* p, int i) { return bf2f(p[i]); }

// ---- dtype sniffer on mlp_v (values in [0.5,1.5]) ----
__global__ void ksniff(const uint* w, int* flag) {
    if (threadIdx.x == 0) {
        int c = 0;
        for (int i = 0; i < 32; ++i) {
            uint lo = w[i] & 0xFFFFu;
            if (lo >= 0x3F00u && lo <= 0x3FC0u) ++c;
        }
        *flag = (c >= 24) ? 0 : 1;  // 0 = bf16 inputs, 1 = f32 inputs
    }
}

// ---- prepack pi/sg/mu weights (128x30 -> f32 [128][32]) + biases ----
template <typename T>
__device__ void prep_w_body(const T* piw, const T* pib, const T* sgw, const T* sgb,
                            const T* muw, const T* mub, float* Wp, float* biasv) {
    int k = threadIdx.x;
#pragma unroll
    for (int g = 0; g < 10; ++g) {
        Wp[k * 32 + g]      = ldv(piw, k * 10 + g);
        Wp[k * 32 + 10 + g] = ldv(sgw, k * 10 + g);
        Wp[k * 32 + 20 + g] = ldv(muw, k * 10 + g);
    }
    Wp[k * 32 + 30] = 0.f; Wp[k * 32 + 31] = 0.f;
    if (k == 0) {
#pragma unroll
        for (int g = 0; g < 10; ++g) {
            biasv[g] = ldv(pib, g); biasv[10 + g] = ldv(sgb, g); biasv[20 + g] = ldv(mub, g);
        }
        biasv[30] = 0.f; biasv[31] = 0.f;
    }
}
__global__ void kprep_w(const void* piw, const void* pib, const void* sgw, const void* sgb,
                        const void* muw, const void* mub, const int* flag, float* Wp, float* biasv) {
    if (*flag) prep_w_body((const float*)piw, (const float*)pib, (const float*)sgw,
                           (const float*)sgb, (const float*)muw, (const float*)mub, Wp, biasv);
    else       prep_w_body((const ushort*)piw, (const ushort*)pib, (const ushort*)sgw,
                           (const ushort*)sgb, (const ushort*)muw, (const ushort*)mub, Wp, biasv);
}

// ---- lig rows: L' = (lig@mlp_w_top)*sM ; SL' = (lig@sel_w1_top)*sS ; atom_types ----
template <typename T>
__device__ void prep_lig_body(const T* lig, const T* mlpw, const T* selw1,
                              const T* mg, const T* mv, const T* sg_, const T* sv,
                              const T* atw, const T* atb,
                              float* Lp, float* SLp, float* out) {
    __shared__ float x[HH];
    int r = blockIdx.x, n = threadIdx.x;
    x[n] = ldv(lig, r * HH + n);
    __syncthreads();
    float accL = 0.f, accS = 0.f;
#pragma unroll 4
    for (int k = 0; k < HH; ++k) {
        float xv = x[k];
        accL = fmaf(xv, ldv(mlpw, k * HH + n), accL);
        accS = fmaf(xv, ldv(selw1, k * HH + n), accS);
    }
    float sM = ldv(mg, n) * rsqrtf(ldv(mv, n) + 1e-5f);
    float sS = ldv(sg_, n) * rsqrtf(ldv(sv, n) + 1e-5f);
    Lp[r * HH + n]  = accL * sM;
    SLp[r * HH + n] = accS * sS;
    if (n < 18) {
        float a = 0.f;
#pragma unroll 4
        for (int k = 0; k < HH; ++k) a = fmaf(x[k], ldv(atw, k * 18 + n), a);
        out[OUT_AT + r * 18 + n] = a + ldv(atb, n);
    }
}
__global__ void kprep_lig(const void* lig, const void* mlpw, const void* selw1,
                          const void* mg, const void* mv, const void* sg_, const void* sv,
                          const void* atw, const void* atb, const int* flag,
                          float* Lp, float* SLp, float* out) {
    if (*flag) prep_lig_body((const float*)lig, (const float*)mlpw, (const float*)selw1,
                             (const float*)mg, (const float*)mv, (const float*)sg_, (const float*)sv,
                             (const float*)atw, (const float*)atb, Lp, SLp, out);
    else       prep_lig_body((const ushort*)lig, (const ushort*)mlpw, (const ushort*)selw1,
                             (const ushort*)mg, (const ushort*)mv, (const ushort*)sg_, (const ushort*)sv,
                             (const ushort*)atw, (const ushort*)atb, Lp, SLp, out);
}

// ---- pro rows (4/block): T' = (pro@mlp_w_bot)*sM + offM, stored bf16; ST' likewise ----
template <typename T>
__device__ void prep_pro_body(const T* pro, const T* mlpw, const T* selw1,
                              const T* mb, const T* mg, const T* mbe, const T* mm, const T* mv,
                              const T* sb1, const T* sg_, const T* sbe, const T* sm, const T* sv,
                              ushort* Tp, ushort* STp) {
    __shared__ float x[4][HH];
    int r0 = blockIdx.x * 4, n = threadIdx.x;
#pragma unroll
    for (int r = 0; r < 4; ++r) x[r][n] = ldv(pro, (r0 + r) * HH + n);
    __syncthreads();
    float aT0 = 0, aT1 = 0, aT2 = 0, aT3 = 0, aS0 = 0, aS1 = 0, aS2 = 0, aS3 = 0;
#pragma unroll 4
    for (int k = 0; k < HH; ++k) {
        float wM = ldv(mlpw, (HH + k) * HH + n);
        float wS = ldv(selw1, (HH + k) * HH + n);
        float x0 = x[0][k], x1 = x[1][k], x2 = x[2][k], x3 = x[3][k];
        aT0 = fmaf(x0, wM, aT0); aS0 = fmaf(x0, wS, aS0);
        aT1 = fmaf(x1, wM, aT1); aS1 = fmaf(x1, wS, aS1);
        aT2 = fmaf(x2, wM, aT2); aS2 = fmaf(x2, wS, aS2);
        aT3 = fmaf(x3, wM, aT3); aS3 = fmaf(x3, wS, aS3);
    }
    float sM = ldv(mg, n) * rsqrtf(ldv(mv, n) + 1e-5f);
    float sS = ldv(sg_, n) * rsqrtf(ldv(sv, n) + 1e-5f);
    float offM = ldv(mb, n) * sM + ldv(mbe, n) - ldv(mm, n) * sM;
    float offS = ldv(sb1, n) * sS + ldv(sbe, n) - ldv(sm, n) * sS;
    Tp[(r0 + 0) * HH + n] = f2bf(aT0 * sM + offM);  STp[(r0 + 0) * HH + n] = f2bf(aS0 * sS + offS);
    Tp[(r0 + 1) * HH + n] = f2bf(aT1 * sM + offM);  STp[(r0 + 1) * HH + n] = f2bf(aS1 * sS + offS);
    Tp[(r0 + 2) * HH + n] = f2bf(aT2 * sM + offM);  STp[(r0 + 2) * HH + n] = f2bf(aS2 * sS + offS);
    Tp[(r0 + 3) * HH + n] = f2bf(aT3 * sM + offM);  STp[(r0 + 3) * HH + n] = f2bf(aS3 * sS + offS);
}
__global__ void kprep_pro(const void* pro, const void* mlpw, const void* selw1,
                          const void* mb, const void* mg, const void* mbe, const void* mm, const void* mv,
                          const void* sb1, const void* sg_, const void* sbe, const void* sm, const void* sv,
                          const int* flag, ushort* Tp, ushort* STp) {
    if (*flag) prep_pro_body((const float*)pro, (const float*)mlpw, (const float*)selw1,
                             (const float*)mb, (const float*)mg, (const float*)mbe, (const float*)mm, (const float*)mv,
                             (const float*)sb1, (const float*)sg_, (const float*)sbe, (const float*)sm, (const float*)sv,
                             Tp, STp);
    else       prep_pro_body((const ushort*)pro, (const ushort*)mlpw, (const ushort*)selw1,
                             (const ushort*)mb, (const ushort*)mg, (const ushort*)mbe, (const ushort*)mm, (const ushort*)mv,
                             (const ushort*)sb1, (const ushort*)sg_, (const ushort*)sbe, (const ushort*)sm, (const ushort*)sv,
                             Tp, STp);
}

// ---- bond types: wave per edge ----
template <typename T>
__device__ void bond_body(const T* lig, const int* edge, const T* btw, const T* btb, float* out) {
    int e = blockIdx.x * 4 + (threadIdx.x >> 6);
    int lane = threadIdx.x & 63;
    int e0 = edge[e], e1 = edge[NE + e];
    int k0 = lane * 2;
    float a0 = ldv(lig, e0 * HH + k0), a1 = ldv(lig, e0 * HH + k0 + 1);
    float b0 = ldv(lig, e1 * HH + k0), b1 = ldv(lig, e1 * HH + k0 + 1);
    float acc[5];
#pragma unroll
    for (int c = 0; c < 5; ++c) {
        acc[c] = a0 * ldv(btw, k0 * 5 + c) + a1 * ldv(btw, (k0 + 1) * 5 + c)
               + b0 * ldv(btw, (HH + k0) * 5 + c) + b1 * ldv(btw, (HH + k0 + 1) * 5 + c);
    }
#pragma unroll
    for (int c = 0; c < 5; ++c)
        for (int off = 32; off > 0; off >>= 1) acc[c] += __shfl_xor(acc[c], off, 64);
    if (lane == 0) {
#pragma unroll
        for (int c = 0; c < 5; ++c) out[OUT_BT + e * 5 + c] = acc[c] + ldv(btb, c);
    }
}
__global__ void kbond(const void* lig, const int* edge, const void* btw, const void* btb,
                      const int* flag, float* out) {
    if (*flag) bond_body((const float*)lig, edge, (const float*)btw, (const float*)btb, out);
    else       bond_body((const ushort*)lig, edge, (const ushort*)btw, (const ushort*)btb, out);
}

// ---- donor selector: wave per donor ----
template <typename T>
__device__ void sel_body(const float* SLp, const ushort* STp, const int* donar,
                         const T* selw2, const T* selb2, float* out) {
    int wid = (blockIdx.x * 256 + threadIdx.x) >> 6;
    int lane = threadIdx.x & 63;
    int d = donar[wid];
    int li = d >> 9;
    int tj = ((d >> 15) << 9) + (d & 511);
    int k0 = lane << 1;
    float x0 = eluf(SLp[li * HH + k0]     + bf2f(STp[tj * HH + k0]));
    float x1 = eluf(SLp[li * HH + k0 + 1] + bf2f(STp[tj * HH + k0 + 1]));
    float s = x0 * ldv(selw2, k0) + x1 * ldv(selw2, k0 + 1);
    for (int off = 32; off > 0; off >>= 1) s += __shfl_xor(s, off, 64);
    if (lane == 0) {
        float z = s + ldv(selb2, 0);
        out[OUT_CD + wid] = 1.f / (1.f + __expf(-z));
    }
}
__global__ void ksel(const float* SLp, const ushort* STp, const int* donar,
                     const void* selw2, const void* selb2, const int* flag, float* out) {
    if (*flag) sel_body(SLp, STp, donar, (const float*)selw2, (const float*)selb2, out);
    else       sel_body(SLp, STp, donar, (const ushort*)selw2, (const ushort*)selb2, out);
}

// ---- main pair kernel: Ch = elu(L'[li]+T'[tj]); 30-wide head; softmax/elu epilogue ----
__global__ __launch_bounds__(256, 4) void kmain(const ushort* __restrict__ Tp, const float* __restrict__ Lp,
                                                const float* __restrict__ Wp, const float* __restrict__ biasv,
                                                float* __restrict__ out) {
    __shared__ float ldsT[64 * 129];
    int bid = blockIdx.x;
    int jt = bid & 7, it = (bid >> 3) & 15, b = bid >> 7;
    int j0 = jt * 64, i0 = it * 4;
    int tid = threadIdx.x;
    const ushort* srcT = Tp + (size_t)(b * NT + j0) * HH;
    for (int t = tid; t < 1024; t += 256) {  // 64 rows x 128 bf16 = 1024 uint4
        uint4 v = ((const uint4*)srcT)[t];
        int j = t >> 4, c0 = (t & 15) * 8;
        float* dst = &ldsT[j * 129 + c0];
        dst[0] = bflo(v.x); dst[1] = bfhi(v.x);
        dst[2] = bflo(v.y); dst[3] = bfhi(v.y);
        dst[4] = bflo(v.z); dst[5] = bfhi(v.z);
        dst[6] = bflo(v.w); dst[7] = bfhi(v.w);
    }
    __syncthreads();
    int lane_j = tid & 63;
    int li = b * NL + i0 + (tid >> 6);         // wave-uniform
    const float* Lrow = Lp + li * HH;
    const float* trow = &ldsT[lane_j * 129];   // 2-way bank alias: free
    float acc[30];
#pragma unroll
    for (int g = 0; g < 30; ++g) acc[g] = 0.f;
#pragma unroll 4
    for (int k = 0; k < HH; ++k) {
        float ch = eluf(Lrow[k] + trow[k]);
        const float* w = Wp + k * 32;          // uniform -> scalar loads
#pragma unroll
        for (int g = 0; g < 30; ++g) acc[g] = fmaf(ch, w[g], acc[g]);
    }
    size_t p = (size_t)li * NT + j0 + lane_j;
    float v0[10], ex[10];
    float mx = -1e30f;
#pragma unroll
    for (int g = 0; g < 10; ++g) { v0[g] = acc[g] + biasv[g]; mx = fmaxf(mx, v0[g]); }
    float s = 0.f;
#pragma unroll
    for (int g = 0; g < 10; ++g) { ex[g] = __expf(v0[g] - mx); s += ex[g]; }
    float inv = 1.f / s;
    float2* opi = (float2*)(out + OUT_PI + p * 10);
#pragma unroll
    for (int gg = 0; gg < 5; ++gg) opi[gg] = make_float2(ex[2 * gg] * inv, ex[2 * gg + 1] * inv);
    float2* osg = (float2*)(out + OUT_SG + p * 10);
#pragma unroll
    for (int gg = 0; gg < 5; ++gg) {
        osg[gg] = make_float2(eluf(acc[10 + 2 * gg] + biasv[10 + 2 * gg]) + 1.1f,
                              eluf(acc[11 + 2 * gg] + biasv[11 + 2 * gg]) + 1.1f);
    }
    float2* omu = (float2*)(out + OUT_MU + p * 10);
#pragma unroll
    for (int gg = 0; gg < 5; ++gg) {
        omu[gg] = make_float2(eluf(acc[20 + 2 * gg] + biasv[20 + 2 * gg]) + 1.0f,
                              eluf(acc[21 + 2 * gg] + biasv[21 + 2 * gg]) + 1.0f);
    }
    out[OUT_CB + p] = (float)b;
    out[OUT_CM + p] = 1.0f;
}

extern "C" void kernel_launch(void* const* d_in, const int* in_sizes, int n_in,
                              void* d_out, int out_size, void* d_ws, size_t ws_size,
                              hipStream_t stream) {
    (void)in_sizes; (void)n_in; (void)out_size; (void)ws_size;
    float* out = (float*)d_out;

    char* wsb = (char*)d_ws;
    float*  Lp    = (float*)(wsb);             // 65536 f32
    float*  SLp   = (float*)(wsb + 262144);    // 65536 f32
    float*  Wp    = (float*)(wsb + 524288);    // 4096 f32
    float*  biasv = (float*)(wsb + 540672);    // 32 f32
    int*    flag  = (int*)  (wsb + 540800);
    ushort* Tp    = (ushort*)(wsb + 540832);   // 524288 bf16 (16B-aligned)
    ushort* STp   = (ushort*)(wsb + 1589408);  // 524288 bf16  -> total ~2.52 MB

    ksniff<<<1, 64, 0, stream>>>((const uint*)d_in[11], flag);
    kprep_w<<<1, 128, 0, stream>>>(d_in[20], d_in[21], d_in[22], d_in[23], d_in[24], d_in[25],
                                   flag, Wp, biasv);
    kprep_lig<<<512, 128, 0, stream>>>(d_in[0], d_in[6], d_in[12], d_in[8], d_in[11],
                                       d_in[14], d_in[17], d_in[26], d_in[27], flag, Lp, SLp, out);
    kprep_pro<<<1024, 128, 0, stream>>>(d_in[1], d_in[6], d_in[12],
                                        d_in[7], d_in[8], d_in[9], d_in[10], d_in[11],
                                        d_in[13], d_in[14], d_in[15], d_in[16], d_in[17],
                                        flag, Tp, STp);
    kbond<<<512, 256, 0, stream>>>(d_in[0], (const int*)d_in[5], d_in[28], d_in[29], flag, out);
    ksel<<<1024, 256, 0, stream>>>(SLp, STp, (const int*)d_in[4], d_in[18], d_in[19], flag, out);
    kmain<<<1024, 256, 0, stream>>>(Tp, Lp, Wp, biasv, out);
}

// Round 4
// 193.032 us; speedup vs baseline: 1.0910x; 1.0910x over previous
//
#include <hip/hip_runtime.h>

#define NL 64
#define NT 512
#define BB 8
#define HH 128
#define NE 2048
#define NM 4096

static constexpr size_t OUT_PI = 0;
static constexpr size_t OUT_SG = 2621440;
static constexpr size_t OUT_MU = 5242880;
static constexpr size_t OUT_CB = 7864320;
static constexpr size_t OUT_AT = 8126464;
static constexpr size_t OUT_BT = 8135680;
static constexpr size_t OUT_CD = 8145920;
static constexpr size_t OUT_CM = 8150016;

__device__ __forceinline__ float bf2f(ushort u) {
    union { uint i; float f; } v; v.i = ((uint)u) << 16; return v.f;
}
__device__ __forceinline__ float bflo(uint u) {
    union { uint i; float f; } v; v.i = u << 16; return v.f;
}
__device__ __forceinline__ float bfhi(uint u) {
    union { uint i; float f; } v; v.i = u & 0xffff0000u; return v.f;
}
__device__ __forceinline__ ushort f2bf(float f) {
    union { float f; uint u; } v; v.f = f;
    uint u = v.u + 0x7fffu + ((v.u >> 16) & 1u);
    return (ushort)(u >> 16);
}
__device__ __forceinline__ float eluf(float x) { return x > 0.f ? x : (__expf(x) - 1.f); }

__device__ __forceinline__ float ldv(const float* p, int i) { return p[i]; }
__device__ __forceinline__ float ldv(const ushort* p, int i) { return bf2f(p[i]); }

// ================= kprep0: dtype sniff + W/bias/selw2 prepack (1 block) ==========
template <typename T>
__device__ void prep_w_body(const T* piw, const T* pib, const T* sgw, const T* sgb,
                            const T* muw, const T* mub, const T* selw2, const T* selb2,
                            float* Wp, float* biasv, float* sel2f) {
    int k = threadIdx.x;
#pragma unroll
    for (int g = 0; g < 10; ++g) {
        Wp[k * 32 + g]      = ldv(piw, k * 10 + g);
        Wp[k * 32 + 10 + g] = ldv(sgw, k * 10 + g);
        Wp[k * 32 + 20 + g] = ldv(muw, k * 10 + g);
    }
    Wp[k * 32 + 30] = 0.f; Wp[k * 32 + 31] = 0.f;
    sel2f[k] = ldv(selw2, k);
    if (k == 0) {
#pragma unroll
        for (int g = 0; g < 10; ++g) {
            biasv[g] = ldv(pib, g); biasv[10 + g] = ldv(sgb, g); biasv[20 + g] = ldv(mub, g);
        }
        biasv[30] = 0.f; biasv[31] = 0.f;
        sel2f[128] = ldv(selb2, 0);
    }
}
__global__ void kprep0(const uint* sniffsrc, const void* piw, const void* pib,
                       const void* sgw, const void* sgb, const void* muw, const void* mub,
                       const void* selw2, const void* selb2,
                       int* flag, float* Wp, float* biasv, float* sel2f) {
    __shared__ int sflag;
    if (threadIdx.x == 0) {
        int c = 0;
        for (int i = 0; i < 32; ++i) {
            uint lo = sniffsrc[i] & 0xFFFFu;
            if (lo >= 0x3F00u && lo <= 0x3FC0u) ++c;
        }
        sflag = (c >= 24) ? 0 : 1;  // 0 = bf16 inputs, 1 = f32 inputs
        *flag = sflag;
    }
    __syncthreads();
    if (sflag) prep_w_body((const float*)piw, (const float*)pib, (const float*)sgw, (const float*)sgb,
                           (const float*)muw, (const float*)mub, (const float*)selw2, (const float*)selb2,
                           Wp, biasv, sel2f);
    else       prep_w_body((const ushort*)piw, (const ushort*)pib, (const ushort*)sgw, (const ushort*)sgb,
                           (const ushort*)muw, (const ushort*)mub, (const ushort*)selw2, (const ushort*)selb2,
                           Wp, biasv, sel2f);
}

// ================= kprep_lig: L'/SL' rows + atom_types ==========
template <typename T>
__device__ void prep_lig_body(const T* lig, const T* mlpw, const T* selw1,
                              const T* mg, const T* mv, const T* sg_, const T* sv,
                              const T* atw, const T* atb,
                              float* Lp, float* SLp, float* out) {
    __shared__ float x[HH];
    int r = blockIdx.x, n = threadIdx.x;
    x[n] = ldv(lig, r * HH + n);
    __syncthreads();
    float accL = 0.f, accS = 0.f;
#pragma unroll 8
    for (int k = 0; k < HH; ++k) {
        float xv = x[k];
        accL = fmaf(xv, ldv(mlpw, k * HH + n), accL);
        accS = fmaf(xv, ldv(selw1, k * HH + n), accS);
    }
    float sM = ldv(mg, n) * rsqrtf(ldv(mv, n) + 1e-5f);
    float sS = ldv(sg_, n) * rsqrtf(ldv(sv, n) + 1e-5f);
    Lp[r * HH + n]  = accL * sM;
    SLp[r * HH + n] = accS * sS;
    if (n < 18) {
        float a = 0.f;
#pragma unroll 8
        for (int k = 0; k < HH; ++k) a = fmaf(x[k], ldv(atw, k * 18 + n), a);
        out[OUT_AT + r * 18 + n] = a + ldv(atb, n);
    }
}
__global__ void kprep_lig(const void* lig, const void* mlpw, const void* selw1,
                          const void* mg, const void* mv, const void* sg_, const void* sv,
                          const void* atw, const void* atb, const int* flag,
                          float* Lp, float* SLp, float* out) {
    if (*flag) prep_lig_body((const float*)lig, (const float*)mlpw, (const float*)selw1,
                             (const float*)mg, (const float*)mv, (const float*)sg_, (const float*)sv,
                             (const float*)atw, (const float*)atb, Lp, SLp, out);
    else       prep_lig_body((const ushort*)lig, (const ushort*)mlpw, (const ushort*)selw1,
                             (const ushort*)mg, (const ushort*)mv, (const ushort*)sg_, (const ushort*)sv,
                             (const ushort*)atw, (const ushort*)atb, Lp, SLp, out);
}

// ================= kprep_pro + bond: T'/ST' rows (bf16) + bond_types ==========
template <typename T>
__device__ void prep_pro_bond_body(const T* pro, const T* mlpw, const T* selw1,
                                   const T* mb, const T* mg, const T* mbe, const T* mm, const T* mv,
                                   const T* sb1, const T* sg_, const T* sbe, const T* sm, const T* sv,
                                   const T* lig, const int* edge, const T* btw, const T* btb,
                                   ushort* Tp, ushort* STp, float* out) {
    __shared__ float x[4][HH];
    int r0 = blockIdx.x * 4, n = threadIdx.x;
#pragma unroll
    for (int r = 0; r < 4; ++r) x[r][n] = ldv(pro, (r0 + r) * HH + n);
    __syncthreads();
    float aT0 = 0, aT1 = 0, aT2 = 0, aT3 = 0, aS0 = 0, aS1 = 0, aS2 = 0, aS3 = 0;
#pragma unroll 4
    for (int k = 0; k < HH; ++k) {
        float wM = ldv(mlpw, (HH + k) * HH + n);
        float wS = ldv(selw1, (HH + k) * HH + n);
        float x0 = x[0][k], x1 = x[1][k], x2 = x[2][k], x3 = x[3][k];
        aT0 = fmaf(x0, wM, aT0); aS0 = fmaf(x0, wS, aS0);
        aT1 = fmaf(x1, wM, aT1); aS1 = fmaf(x1, wS, aS1);
        aT2 = fmaf(x2, wM, aT2); aS2 = fmaf(x2, wS, aS2);
        aT3 = fmaf(x3, wM, aT3); aS3 = fmaf(x3, wS, aS3);
    }
    float sM = ldv(mg, n) * rsqrtf(ldv(mv, n) + 1e-5f);
    float sS = ldv(sg_, n) * rsqrtf(ldv(sv, n) + 1e-5f);
    float offM = ldv(mb, n) * sM + ldv(mbe, n) - ldv(mm, n) * sM;
    float offS = ldv(sb1, n) * sS + ldv(sbe, n) - ldv(sm, n) * sS;
    Tp[(r0 + 0) * HH + n] = f2bf(aT0 * sM + offM);  STp[(r0 + 0) * HH + n] = f2bf(aS0 * sS + offS);
    Tp[(r0 + 1) * HH + n] = f2bf(aT1 * sM + offM);  STp[(r0 + 1) * HH + n] = f2bf(aS1 * sS + offS);
    Tp[(r0 + 2) * HH + n] = f2bf(aT2 * sM + offM);  STp[(r0 + 2) * HH + n] = f2bf(aS2 * sS + offS);
    Tp[(r0 + 3) * HH + n] = f2bf(aT3 * sM + offM);  STp[(r0 + 3) * HH + n] = f2bf(aS3 * sS + offS);

    // ---- bond tail: 2 edges per block, one per wave ----
    int widx = n >> 6, lane = n & 63;
    int e = blockIdx.x * 2 + widx;
    int e0 = edge[e], e1 = edge[NE + e];
    int k0 = lane * 2;
    float a0 = ldv(lig, e0 * HH + k0), a1 = ldv(lig, e0 * HH + k0 + 1);
    float b0 = ldv(lig, e1 * HH + k0), b1 = ldv(lig, e1 * HH + k0 + 1);
    float acc[5];
#pragma unroll
    for (int c = 0; c < 5; ++c) {
        acc[c] = a0 * ldv(btw, k0 * 5 + c) + a1 * ldv(btw, (k0 + 1) * 5 + c)
               + b0 * ldv(btw, (HH + k0) * 5 + c) + b1 * ldv(btw, (HH + k0 + 1) * 5 + c);
    }
#pragma unroll
    for (int c = 0; c < 5; ++c)
        for (int off = 32; off > 0; off >>= 1) acc[c] += __shfl_xor(acc[c], off, 64);
    if (lane == 0) {
#pragma unroll
        for (int c = 0; c < 5; ++c) out[OUT_BT + e * 5 + c] = acc[c] + ldv(btb, c);
    }
}
__global__ void kprep_pro_bond(const void* pro, const void* mlpw, const void* selw1,
                               const void* mb, const void* mg, const void* mbe, const void* mm, const void* mv,
                               const void* sb1, const void* sg_, const void* sbe, const void* sm, const void* sv,
                               const void* lig, const int* edge, const void* btw, const void* btb,
                               const int* flag, ushort* Tp, ushort* STp, float* out) {
    if (*flag) prep_pro_bond_body((const float*)pro, (const float*)mlpw, (const float*)selw1,
                                  (const float*)mb, (const float*)mg, (const float*)mbe, (const float*)mm, (const float*)mv,
                                  (const float*)sb1, (const float*)sg_, (const float*)sbe, (const float*)sm, (const float*)sv,
                                  (const float*)lig, edge, (const float*)btw, (const float*)btb, Tp, STp, out);
    else       prep_pro_bond_body((const ushort*)pro, (const ushort*)mlpw, (const ushort*)selw1,
                                  (const ushort*)mb, (const ushort*)mg, (const ushort*)mbe, (const ushort*)mm, (const ushort*)mv,
                                  (const ushort*)sb1, (const ushort*)sg_, (const ushort*)sbe, (const ushort*)sm, (const ushort*)sv,
                                  (const ushort*)lig, edge, (const ushort*)btw, (const ushort*)btb, Tp, STp, out);
}

// ================= kmain: pairs + donor-selector tail ==========
// LDS: T tile as bf16-pair uints [64][65] (2-way banks, free) + L rows f32 [4][132]
__global__ __launch_bounds__(256, 4) void kmain(const ushort* __restrict__ Tp, const float* __restrict__ Lp,
                                                const float* __restrict__ Wp, const float* __restrict__ biasv,
                                                const float* __restrict__ SLp, const ushort* __restrict__ STp,
                                                const int* __restrict__ donar, const float* __restrict__ sel2f,
                                                float* __restrict__ out) {
    __shared__ uint  ldsTu[64 * 65];
    __shared__ float ldsL[4 * 132];
    int bid = blockIdx.x;
    int jt = bid & 7, it = (bid >> 3) & 15, b = bid >> 7;
    int j0 = jt * 64, i0 = it * 4;
    int tid = threadIdx.x;

    const uint* srcT = (const uint*)(Tp + (size_t)(b * NT + j0) * HH);
#pragma unroll
    for (int q = 0; q < 4; ++q) {          // 1024 uint4 = 64 rows x 16
        int t = tid + q * 256;
        uint4 v = ((const uint4*)srcT)[t];
        int j = t >> 4, c0 = (t & 15) * 4;
        uint* dst = &ldsTu[j * 65 + c0];
        dst[0] = v.x; dst[1] = v.y; dst[2] = v.z; dst[3] = v.w;
    }
    if (tid < 128) {                        // 4 L rows x 32 float4
        int r = tid >> 5, c = (tid & 31) * 4;
        float4 v = *(const float4*)(Lp + (size_t)(b * NL + i0 + r) * HH + c);
        *(float4*)&ldsL[r * 132 + c] = v;
    }
    __syncthreads();

    int lane_j = tid & 63, widx = tid >> 6;
    const uint*  trowp = &ldsTu[lane_j * 65];
    const float* lsrow = &ldsL[widx * 132];
    float acc[30];
#pragma unroll
    for (int g = 0; g < 30; ++g) acc[g] = 0.f;
#pragma unroll 8
    for (int m = 0; m < 64; ++m) {
        uint tp2 = trowp[m];
        float ch0 = eluf(lsrow[2 * m]     + bflo(tp2));
        float ch1 = eluf(lsrow[2 * m + 1] + bfhi(tp2));
        const float* w0 = Wp + (2 * m) * 32;
        const float* w1 = Wp + (2 * m + 1) * 32;
#pragma unroll
        for (int g = 0; g < 30; ++g)
            acc[g] = fmaf(ch1, w1[g], fmaf(ch0, w0[g], acc[g]));
    }

    int li = b * NL + i0 + widx;
    size_t p = (size_t)li * NT + j0 + lane_j;
    float v0[10], ex[10];
    float mx = -1e30f;
#pragma unroll
    for (int g = 0; g < 10; ++g) { v0[g] = acc[g] + biasv[g]; mx = fmaxf(mx, v0[g]); }
    float s = 0.f;
#pragma unroll
    for (int g = 0; g < 10; ++g) { ex[g] = __expf(v0[g] - mx); s += ex[g]; }
    float inv = 1.f / s;
    float2* opi = (float2*)(out + OUT_PI + p * 10);
#pragma unroll
    for (int gg = 0; gg < 5; ++gg) opi[gg] = make_float2(ex[2 * gg] * inv, ex[2 * gg + 1] * inv);
    float2* osg = (float2*)(out + OUT_SG + p * 10);
#pragma unroll
    for (int gg = 0; gg < 5; ++gg) {
        osg[gg] = make_float2(eluf(acc[10 + 2 * gg] + biasv[10 + 2 * gg]) + 1.1f,
                              eluf(acc[11 + 2 * gg] + biasv[11 + 2 * gg]) + 1.1f);
    }
    float2* omu = (float2*)(out + OUT_MU + p * 10);
#pragma unroll
    for (int gg = 0; gg < 5; ++gg) {
        omu[gg] = make_float2(eluf(acc[20 + 2 * gg] + biasv[20 + 2 * gg]) + 1.0f,
                              eluf(acc[21 + 2 * gg] + biasv[21 + 2 * gg]) + 1.0f);
    }
    out[OUT_CB + p] = (float)b;
    out[OUT_CM + p] = 1.0f;

    // ---- donor-selector tail: wave w handles donar[w] ----
    int w = bid * 4 + widx;
    int d = donar[w];
    int dli = d >> 9;
    int dtj = ((d >> 15) << 9) + (d & 511);
    int k0 = lane_j << 1;
    float2 sl = *(const float2*)(SLp + (size_t)dli * HH + k0);
    uint stp = ((const uint*)STp)[dtj * 64 + lane_j];
    float x0 = eluf(sl.x + bflo(stp));
    float x1 = eluf(sl.y + bfhi(stp));
    float ssum = x0 * sel2f[k0] + x1 * sel2f[k0 + 1];
    for (int off = 32; off > 0; off >>= 1) ssum += __shfl_xor(ssum, off, 64);
    if (lane_j == 0) {
        float z = ssum + sel2f[128];
        out[OUT_CD + w] = 1.f / (1.f + __expf(-z));
    }
}

extern "C" void kernel_launch(void* const* d_in, const int* in_sizes, int n_in,
                              void* d_out, int out_size, void* d_ws, size_t ws_size,
                              hipStream_t stream) {
    (void)in_sizes; (void)n_in; (void)out_size; (void)ws_size;
    float* out = (float*)d_out;

    char* wsb = (char*)d_ws;
    float*  Lp    = (float*)(wsb);             // 65536 f32
    float*  SLp   = (float*)(wsb + 262144);    // 65536 f32
    float*  Wp    = (float*)(wsb + 524288);    // 4096 f32
    float*  biasv = (float*)(wsb + 540672);    // 32 f32
    float*  sel2f = (float*)(wsb + 540800);    // 129 f32
    int*    flag  = (int*)  (wsb + 541328);
    ushort* Tp    = (ushort*)(wsb + 541344);   // 524288 bf16
    ushort* STp   = (ushort*)(wsb + 1589920);  // 524288 bf16

    kprep0<<<1, 128, 0, stream>>>((const uint*)d_in[11], d_in[20], d_in[21], d_in[22], d_in[23],
                                  d_in[24], d_in[25], d_in[18], d_in[19], flag, Wp, biasv, sel2f);
    kprep_lig<<<512, 128, 0, stream>>>(d_in[0], d_in[6], d_in[12], d_in[8], d_in[11],
                                       d_in[14], d_in[17], d_in[26], d_in[27], flag, Lp, SLp, out);
    kprep_pro_bond<<<1024, 128, 0, stream>>>(d_in[1], d_in[6], d_in[12],
                                             d_in[7], d_in[8], d_in[9], d_in[10], d_in[11],
                                             d_in[13], d_in[14], d_in[15], d_in[16], d_in[17],
                                             d_in[0], (const int*)d_in[5], d_in[28], d_in[29],
                                             flag, Tp, STp, out);
    kmain<<<1024, 256, 0, stream>>>(Tp, Lp, Wp, biasv, SLp, STp, (const int*)d_in[4], sel2f, out);
}

// Round 5
// 161.465 us; speedup vs baseline: 1.3043x; 1.1955x over previous
//
#include <hip/hip_runtime.h>

#define NL 64
#define NT 512
#define BB 8
#define HH 128
#define NE 2048
#define NM 4096

static constexpr size_t OUT_PI = 0;
static constexpr size_t OUT_SG = 2621440;
static constexpr size_t OUT_MU = 5242880;
static constexpr size_t OUT_CB = 7864320;
static constexpr size_t OUT_AT = 8126464;
static constexpr size_t OUT_BT = 8135680;
static constexpr size_t OUT_CD = 8145920;
static constexpr size_t OUT_CM = 8150016;

typedef __attribute__((ext_vector_type(8))) short bf16x8;
typedef __attribute__((ext_vector_type(4))) float f32x4;

__device__ __forceinline__ float bf2f(ushort u) {
    union { uint i; float f; } v; v.i = ((uint)u) << 16; return v.f;
}
__device__ __forceinline__ float bflo(uint u) {
    union { uint i; float f; } v; v.i = u << 16; return v.f;
}
__device__ __forceinline__ float bfhi(uint u) {
    union { uint i; float f; } v; v.i = u & 0xffff0000u; return v.f;
}
__device__ __forceinline__ ushort f2bf(float f) {
    union { float f; uint u; } v; v.f = f;
    uint u = v.u + 0x7fffu + ((v.u >> 16) & 1u);
    return (ushort)(u >> 16);
}
__device__ __forceinline__ float eluf(float x) { return x > 0.f ? x : (__expf(x) - 1.f); }
// pack elu(a),elu(b) to bf16x2 with +0.5ulp rounding (cheap RTN)
__device__ __forceinline__ uint pkelu2(float a, float b) {
    a = eluf(a); b = eluf(b);
    union { float f; uint u; } ua, ub; ua.f = a; ub.f = b;
    return ((ua.u + 0x8000u) >> 16) | ((ub.u + 0x8000u) & 0xffff0000u);
}

__device__ __forceinline__ float ldv(const float* p, int i) { return p[i]; }
__device__ __forceinline__ float ldv(const ushort* p, int i) { return bf2f(p[i]); }

// ======================= fused prep kernel =======================
template <typename T>
__device__ void prep_lig_part(int r, const T* lig, const T* mlpw, const T* selw1,
                              const T* mg, const T* mv, const T* sg_, const T* sv,
                              const T* atw, const T* atb,
                              float* Lp, float* SLp, float* out) {
    __shared__ float x[HH];
    int n = threadIdx.x;
    x[n] = ldv(lig, r * HH + n);
    __syncthreads();
    float accL = 0.f, accS = 0.f;
#pragma unroll 8
    for (int k = 0; k < HH; ++k) {
        float xv = x[k];
        accL = fmaf(xv, ldv(mlpw, k * HH + n), accL);
        accS = fmaf(xv, ldv(selw1, k * HH + n), accS);
    }
    float sM = ldv(mg, n) * rsqrtf(ldv(mv, n) + 1e-5f);
    float sS = ldv(sg_, n) * rsqrtf(ldv(sv, n) + 1e-5f);
    Lp[r * HH + n]  = accL * sM;
    SLp[r * HH + n] = accS * sS;
    if (n < 18) {
        float a = 0.f;
#pragma unroll 8
        for (int k = 0; k < HH; ++k) a = fmaf(x[k], ldv(atw, k * 18 + n), a);
        out[OUT_AT + r * 18 + n] = a + ldv(atb, n);
    }
}

template <typename T>
__device__ void prep_pro_bond_part(int pb, const T* pro, const T* mlpw, const T* selw1,
                                   const T* mb, const T* mg, const T* mbe, const T* mm, const T* mv,
                                   const T* sb1, const T* sg_, const T* sbe, const T* sm, const T* sv,
                                   const T* lig, const int* edge, const T* btw, const T* btb,
                                   ushort* Tp, ushort* STp, float* out) {
    __shared__ float x[4][HH];
    int r0 = pb * 4, n = threadIdx.x;
#pragma unroll
    for (int r = 0; r < 4; ++r) x[r][n] = ldv(pro, (r0 + r) * HH + n);
    __syncthreads();
    float aT0 = 0, aT1 = 0, aT2 = 0, aT3 = 0, aS0 = 0, aS1 = 0, aS2 = 0, aS3 = 0;
#pragma unroll 4
    for (int k = 0; k < HH; ++k) {
        float wM = ldv(mlpw, (HH + k) * HH + n);
        float wS = ldv(selw1, (HH + k) * HH + n);
        float x0 = x[0][k], x1 = x[1][k], x2 = x[2][k], x3 = x[3][k];
        aT0 = fmaf(x0, wM, aT0); aS0 = fmaf(x0, wS, aS0);
        aT1 = fmaf(x1, wM, aT1); aS1 = fmaf(x1, wS, aS1);
        aT2 = fmaf(x2, wM, aT2); aS2 = fmaf(x2, wS, aS2);
        aT3 = fmaf(x3, wM, aT3); aS3 = fmaf(x3, wS, aS3);
    }
    float sM = ldv(mg, n) * rsqrtf(ldv(mv, n) + 1e-5f);
    float sS = ldv(sg_, n) * rsqrtf(ldv(sv, n) + 1e-5f);
    float offM = ldv(mb, n) * sM + ldv(mbe, n) - ldv(mm, n) * sM;
    float offS = ldv(sb1, n) * sS + ldv(sbe, n) - ldv(sm, n) * sS;
    Tp[(r0 + 0) * HH + n] = f2bf(aT0 * sM + offM);  STp[(r0 + 0) * HH + n] = f2bf(aS0 * sS + offS);
    Tp[(r0 + 1) * HH + n] = f2bf(aT1 * sM + offM);  STp[(r0 + 1) * HH + n] = f2bf(aS1 * sS + offS);
    Tp[(r0 + 2) * HH + n] = f2bf(aT2 * sM + offM);  STp[(r0 + 2) * HH + n] = f2bf(aS2 * sS + offS);
    Tp[(r0 + 3) * HH + n] = f2bf(aT3 * sM + offM);  STp[(r0 + 3) * HH + n] = f2bf(aS3 * sS + offS);

    // bond tail: 2 edges per block, one per wave
    int widx = n >> 6, lane = n & 63;
    int e = pb * 2 + widx;
    int e0 = edge[e], e1 = edge[NE + e];
    int k0 = lane * 2;
    float a0 = ldv(lig, e0 * HH + k0), a1 = ldv(lig, e0 * HH + k0 + 1);
    float b0 = ldv(lig, e1 * HH + k0), b1 = ldv(lig, e1 * HH + k0 + 1);
    float acc[5];
#pragma unroll
    for (int c = 0; c < 5; ++c) {
        acc[c] = a0 * ldv(btw, k0 * 5 + c) + a1 * ldv(btw, (k0 + 1) * 5 + c)
               + b0 * ldv(btw, (HH + k0) * 5 + c) + b1 * ldv(btw, (HH + k0 + 1) * 5 + c);
    }
#pragma unroll
    for (int c = 0; c < 5; ++c)
        for (int off = 32; off > 0; off >>= 1) acc[c] += __shfl_xor(acc[c], off, 64);
    if (lane == 0) {
#pragma unroll
        for (int c = 0; c < 5; ++c) out[OUT_BT + e * 5 + c] = acc[c] + ldv(btb, c);
    }
}

// W prep: build MFMA B-fragments. Wb[(tile*4+ks)*64 + lane] = 8 bf16:
// element j -> W_head[k = ks*32 + (lane>>4)*8 + j][n = lane&15], n>=10 -> 0.
template <typename T>
__device__ void prep_w_part(const T* piw, const T* pib, const T* sgw, const T* sgb,
                            const T* muw, const T* mub, const T* selw2, const T* selb2,
                            uint4* Wb, float* biasv, float* sel2f) {
    int t = threadIdx.x;
    for (int f = t; f < 768; f += 128) {
        int tile = f >> 8, ks = (f >> 6) & 3, ln = f & 63;
        int n = ln & 15, q = ln >> 4;
        const T* Wh = (tile == 0) ? piw : ((tile == 1) ? sgw : muw);
        uint pr[4];
#pragma unroll
        for (int tt = 0; tt < 4; ++tt) {
            int k = ks * 32 + q * 8 + 2 * tt;
            ushort lo = (n < 10) ? f2bf(ldv(Wh, k * 10 + n)) : (ushort)0;
            ushort hi = (n < 10) ? f2bf(ldv(Wh, (k + 1) * 10 + n)) : (ushort)0;
            pr[tt] = (uint)lo | ((uint)hi << 16);
        }
        uint4 u; u.x = pr[0]; u.y = pr[1]; u.z = pr[2]; u.w = pr[3];
        Wb[f] = u;
    }
    sel2f[t] = ldv(selw2, t);
    if (t == 0) {
#pragma unroll
        for (int g = 0; g < 10; ++g) {
            biasv[g] = ldv(pib, g); biasv[10 + g] = ldv(sgb, g); biasv[20 + g] = ldv(mub, g);
        }
        biasv[30] = 0.f; biasv[31] = 0.f;
        sel2f[128] = ldv(selb2, 0);
    }
}

template <typename T>
__device__ void prep_all_body(int bid,
    const T* lig, const T* pro, const T* mlpw, const T* selw1,
    const T* mb, const T* mg, const T* mbe, const T* mm, const T* mv,
    const T* sb1, const T* sg_, const T* sbe, const T* sm, const T* sv,
    const T* atw, const T* atb, const T* btw, const T* btb,
    const T* piw, const T* pib, const T* sgw, const T* sgb, const T* muw, const T* mub,
    const T* selw2, const T* selb2, const int* edge,
    float* Lp, float* SLp, ushort* Tp, ushort* STp, uint4* Wb, float* biasv, float* sel2f,
    float* out) {
    if (bid < 512) {
        prep_lig_part(bid, lig, mlpw, selw1, mg, mv, sg_, sv, atw, atb, Lp, SLp, out);
    } else if (bid < 1536) {
        prep_pro_bond_part(bid - 512, pro, mlpw, selw1, mb, mg, mbe, mm, mv,
                           sb1, sg_, sbe, sm, sv, lig, edge, btw, btb, Tp, STp, out);
    } else {
        prep_w_part(piw, pib, sgw, sgb, muw, mub, selw2, selb2, Wb, biasv, sel2f);
    }
}

__global__ void kprep_all(
    const void* lig, const void* pro, const void* mlpw, const void* selw1,
    const void* mb, const void* mg, const void* mbe, const void* mm, const void* mv,
    const void* sb1, const void* sg_, const void* sbe, const void* sm, const void* sv,
    const void* atw, const void* atb, const void* btw, const void* btb,
    const void* piw, const void* pib, const void* sgw, const void* sgb, const void* muw, const void* mub,
    const void* selw2, const void* selb2, const int* edge,
    float* Lp, float* SLp, ushort* Tp, ushort* STp, uint4* Wb, float* biasv, float* sel2f,
    float* out) {
    // inline dtype sniff on mlp_v (values in [0.5,1.5]; bf16 low-halfword pattern test)
    const uint* w = (const uint*)mv;
    int c = 0;
#pragma unroll
    for (int i = 0; i < 32; ++i) { uint lo = w[i] & 0xFFFFu; c += (lo >= 0x3F00u && lo <= 0x3FC0u); }
    int bid = blockIdx.x;
    if (c < 24) {  // f32 inputs
        prep_all_body(bid, (const float*)lig, (const float*)pro, (const float*)mlpw, (const float*)selw1,
                      (const float*)mb, (const float*)mg, (const float*)mbe, (const float*)mm, (const float*)mv,
                      (const float*)sb1, (const float*)sg_, (const float*)sbe, (const float*)sm, (const float*)sv,
                      (const float*)atw, (const float*)atb, (const float*)btw, (const float*)btb,
                      (const float*)piw, (const float*)pib, (const float*)sgw, (const float*)sgb,
                      (const float*)muw, (const float*)mub, (const float*)selw2, (const float*)selb2,
                      edge, Lp, SLp, Tp, STp, Wb, biasv, sel2f, out);
    } else {       // bf16 inputs
        prep_all_body(bid, (const ushort*)lig, (const ushort*)pro, (const ushort*)mlpw, (const ushort*)selw1,
                      (const ushort*)mb, (const ushort*)mg, (const ushort*)mbe, (const ushort*)mm, (const ushort*)mv,
                      (const ushort*)sb1, (const ushort*)sg_, (const ushort*)sbe, (const ushort*)sm, (const ushort*)sv,
                      (const ushort*)atw, (const ushort*)atb, (const ushort*)btw, (const ushort*)btb,
                      (const ushort*)piw, (const ushort*)pib, (const ushort*)sgw, (const ushort*)sgb,
                      (const ushort*)muw, (const ushort*)mub, (const ushort*)selw2, (const ushort*)selb2,
                      edge, Lp, SLp, Tp, STp, Wb, biasv, sel2f, out);
    }
}

// ======================= kmain: MFMA pair kernel =======================
// Per block: 4 i-rows (one per wave) x 64 j. Per wave: 4 M-tiles of 16 j,
// K=128 in 4 steps of 32, 3 N-tiles (pi/sg/mu, cols 0-9 real + 6 zero-pad).
// A = elu(L_i + T_j) packed bf16 on the fly; D repacked pair-major via
// per-wave LDS region (no barriers). Epilogue identical to R4's proven code.
__global__ __launch_bounds__(256) void kmain(
    const ushort* __restrict__ Tp, const float* __restrict__ Lp, const uint4* __restrict__ Wb,
    const float* __restrict__ biasv, const float* __restrict__ SLp, const ushort* __restrict__ STp,
    const int* __restrict__ donar, const float* __restrict__ sel2f, float* __restrict__ out) {
    __shared__ float ep[4 * 64 * 33];  // per-wave 64 pairs x 33 (stride-33: conflict-free readback)
    int bid = blockIdx.x, tid = threadIdx.x;
    int jt = bid & 7, it = (bid >> 3) & 15, b = bid >> 7;
    int j0 = jt * 64, i0 = it * 4;
    int lane = tid & 63, widx = tid >> 6;
    int m16 = lane & 15, quad = lane >> 4;

    // this wave's L row -> registers (k = ks*32 + quad*8 + [0,8))
    const float* Lg = Lp + (size_t)(b * NL + i0 + widx) * HH + quad * 8;
    f32x4 Lr[4][2];
#pragma unroll
    for (int ks = 0; ks < 4; ++ks) {
        Lr[ks][0] = *(const f32x4*)(Lg + ks * 32);
        Lr[ks][1] = *(const f32x4*)(Lg + ks * 32 + 4);
    }

    const ushort* Tbase = Tp + (size_t)(b * NT + j0) * HH;
    f32x4 acc[4][3];
#pragma unroll
    for (int mt = 0; mt < 4; ++mt)
#pragma unroll
        for (int t = 0; t < 3; ++t) acc[mt][t] = (f32x4){0.f, 0.f, 0.f, 0.f};

#pragma unroll
    for (int ks = 0; ks < 4; ++ks) {
        bf16x8 Bfr[3];
#pragma unroll
        for (int t = 0; t < 3; ++t) {
            uint4 wv = Wb[(t * 4 + ks) * 64 + lane];
            Bfr[t] = *(bf16x8*)&wv;
        }
        float l0 = Lr[ks][0][0], l1 = Lr[ks][0][1], l2 = Lr[ks][0][2], l3 = Lr[ks][0][3];
        float l4 = Lr[ks][1][0], l5 = Lr[ks][1][1], l6 = Lr[ks][1][2], l7 = Lr[ks][1][3];
#pragma unroll
        for (int mt = 0; mt < 4; ++mt) {
            // A rows = 16 j's; lane reads its row m16, k-chunk quad*8 (16B, L1-hot)
            uint4 tv = *(const uint4*)(Tbase + (size_t)(mt * 16 + m16) * HH + ks * 32 + quad * 8);
            uint4 af;
            af.x = pkelu2(l0 + bflo(tv.x), l1 + bfhi(tv.x));
            af.y = pkelu2(l2 + bflo(tv.y), l3 + bfhi(tv.y));
            af.z = pkelu2(l4 + bflo(tv.z), l5 + bfhi(tv.z));
            af.w = pkelu2(l6 + bflo(tv.w), l7 + bfhi(tv.w));
            bf16x8 A = *(bf16x8*)&af;
            acc[mt][0] = __builtin_amdgcn_mfma_f32_16x16x32_bf16(A, Bfr[0], acc[mt][0], 0, 0, 0);
            acc[mt][1] = __builtin_amdgcn_mfma_f32_16x16x32_bf16(A, Bfr[1], acc[mt][1], 0, 0, 0);
            acc[mt][2] = __builtin_amdgcn_mfma_f32_16x16x32_bf16(A, Bfr[2], acc[mt][2], 0, 0, 0);
        }
    }

    // D layout: col n = lane&15, row m = (lane>>4)*4 + reg (m89-verified).
    // Scatter real cols (n<10) pair-major into this wave's LDS region.
    float* myep = ep + widx * 2112;
    if (m16 < 10) {
#pragma unroll
        for (int mt = 0; mt < 4; ++mt)
#pragma unroll
            for (int t = 0; t < 3; ++t)
#pragma unroll
                for (int r = 0; r < 4; ++r)
                    myep[(mt * 16 + quad * 4 + r) * 33 + t * 10 + m16] = acc[mt][t][r];
    }
    float a2[30];
    const float* arow = myep + lane * 33;
#pragma unroll
    for (int g = 0; g < 30; ++g) a2[g] = arow[g];

    int li = b * NL + i0 + widx;
    size_t p = (size_t)li * NT + j0 + lane;
    float v0[10], exv[10];
    float mx = -1e30f;
#pragma unroll
    for (int g = 0; g < 10; ++g) { v0[g] = a2[g] + biasv[g]; mx = fmaxf(mx, v0[g]); }
    float s = 0.f;
#pragma unroll
    for (int g = 0; g < 10; ++g) { exv[g] = __expf(v0[g] - mx); s += exv[g]; }
    float inv = 1.f / s;
    float2* opi = (float2*)(out + OUT_PI + p * 10);
#pragma unroll
    for (int gg = 0; gg < 5; ++gg) opi[gg] = make_float2(exv[2 * gg] * inv, exv[2 * gg + 1] * inv);
    float2* osg = (float2*)(out + OUT_SG + p * 10);
#pragma unroll
    for (int gg = 0; gg < 5; ++gg) {
        osg[gg] = make_float2(eluf(a2[10 + 2 * gg] + biasv[10 + 2 * gg]) + 1.1f,
                              eluf(a2[11 + 2 * gg] + biasv[11 + 2 * gg]) + 1.1f);
    }
    float2* omu = (float2*)(out + OUT_MU + p * 10);
#pragma unroll
    for (int gg = 0; gg < 5; ++gg) {
        omu[gg] = make_float2(eluf(a2[20 + 2 * gg] + biasv[20 + 2 * gg]) + 1.0f,
                              eluf(a2[21 + 2 * gg] + biasv[21 + 2 * gg]) + 1.0f);
    }
    out[OUT_CB + p] = (float)b;
    out[OUT_CM + p] = 1.0f;

    // donor-selector tail: wave w handles donar[w]
    int w = bid * 4 + widx;
    int d = donar[w];
    int dli = d >> 9;
    int dtj = ((d >> 15) << 9) + (d & 511);
    int k0 = lane << 1;
    float2 sl = *(const float2*)(SLp + (size_t)dli * HH + k0);
    uint stp = ((const uint*)STp)[dtj * 64 + lane];
    float x0 = eluf(sl.x + bflo(stp));
    float x1 = eluf(sl.y + bfhi(stp));
    float ssum = x0 * sel2f[k0] + x1 * sel2f[k0 + 1];
    for (int off = 32; off > 0; off >>= 1) ssum += __shfl_xor(ssum, off, 64);
    if (lane == 0) {
        float z = ssum + sel2f[128];
        out[OUT_CD + w] = 1.f / (1.f + __expf(-z));
    }
}

extern "C" void kernel_launch(void* const* d_in, const int* in_sizes, int n_in,
                              void* d_out, int out_size, void* d_ws, size_t ws_size,
                              hipStream_t stream) {
    (void)in_sizes; (void)n_in; (void)out_size; (void)ws_size;
    float* out = (float*)d_out;

    char* wsb = (char*)d_ws;
    float*  Lp    = (float*)(wsb);              // 65536 f32
    float*  SLp   = (float*)(wsb + 262144);     // 65536 f32
    uint4*  Wb    = (uint4*)(wsb + 524288);     // 768 x 16 B
    float*  biasv = (float*)(wsb + 536576);     // 32 f32
    float*  sel2f = (float*)(wsb + 536704);     // 129 f32 (+pad)
    ushort* Tp    = (ushort*)(wsb + 537248);    // 524288 bf16 (16B aligned)
    ushort* STp   = (ushort*)(wsb + 1585824);   // 524288 bf16

    kprep_all<<<1537, 128, 0, stream>>>(
        d_in[0], d_in[1], d_in[6], d_in[12],
        d_in[7], d_in[8], d_in[9], d_in[10], d_in[11],
        d_in[13], d_in[14], d_in[15], d_in[16], d_in[17],
        d_in[26], d_in[27], d_in[28], d_in[29],
        d_in[20], d_in[21], d_in[22], d_in[23], d_in[24], d_in[25],
        d_in[18], d_in[19], (const int*)d_in[5],
        Lp, SLp, Tp, STp, Wb, biasv, sel2f, out);
    kmain<<<1024, 256, 0, stream>>>(Tp, Lp, Wb, biasv, SLp, STp, (const int*)d_in[4], sel2f, out);
}